// Round 14
// baseline (1392.831 us; speedup 1.0000x reference)
//
#include <hip/hip_runtime.h>
#include <hip/hip_bf16.h>
#include <math.h>

#define BB 512
#define TT 80
#define VV 80
#define DD 128
#define HH 256
#define FH 1024
#define EE 8
#define GG1 512
#define GG2 256
#define MT 16
#define NT 72
#define SLOTS (NT*MT)   // 1152
#define CCK 16          // chunk length (5 chunks); skewed fusion across chunks

typedef __attribute__((ext_vector_type(8))) short bf16x8;
typedef __attribute__((ext_vector_type(4))) float f32x4;
typedef __attribute__((ext_vector_type(4))) unsigned int u32x4;

__device__ __forceinline__ float bf2f(unsigned short u) {
    unsigned int v = ((unsigned int)u) << 16;
    return __builtin_bit_cast(float, v);
}
__device__ __forceinline__ unsigned short f2bf(float f) {
    __hip_bfloat16 h = __float2bfloat16(f);
    return __builtin_bit_cast(unsigned short, h);
}
__device__ __forceinline__ float sigm(float x) { return 1.f / (1.f + __expf(-x)); }
__device__ __forceinline__ float tanh_f(float x) {
    float ax = fabsf(x);
    float r = 1.f - 2.f / (__expf(2.f * ax) + 1.f);
    return x < 0.f ? -r : r;
}

// ---------------- prep: pack recurrent weights (full-width wave layout) + Wih1 + bias sums --------
// WR: [e][w(8)][kb(8)][nf(8)][lane(64)][j(8)]   nf = g*2 + hc
//     elem = W[gc][kk]; gc = g*256 + w*32 + hc*16 + (l&15); kk = kb*32 + (l>>4)*8 + j
// WG: [e][gf(64)][kb(8)][lane(64)][j(8)]  elem = Wih1[gf*16+(l&15)][kb*32+(l>>4)*8+j]
__global__ void prep_kernel(const float* __restrict__ Whh0, const float* __restrict__ Wih1,
                            const float* __restrict__ Whh1,
                            const float* __restrict__ bih1, const float* __restrict__ bhh1,
                            unsigned short* __restrict__ WR0, unsigned short* __restrict__ WR1,
                            unsigned short* __restrict__ WG, float* __restrict__ bsum1)
{
    const int NB = 262144;                 // entry groups of 8 per array
    const int ntot = 3 * NB + EE * FH;
    for (int idx = blockIdx.x * blockDim.x + threadIdx.x; idx < ntot;
         idx += gridDim.x * blockDim.x) {
        if (idx < 3 * NB) {
            int arr = idx / NB;
            int p = idx - arr * NB;
            int gc, kk, e;
            const float* src;
            if (arr < 2) {
                int l = p & 63, nf = (p >> 6) & 7, kb = (p >> 9) & 7, w = (p >> 12) & 7;
                e = (p >> 15) & 7;
                int g = nf >> 1, hc = nf & 1;
                gc = g * 256 + w * 32 + hc * 16 + (l & 15);
                kk = kb * 32 + ((l >> 4) * 8);
                src = (arr == 0) ? Whh0 : Whh1;
            } else {
                int l = p & 63, kb = (p >> 6) & 7, gf = (p >> 9) & 63; e = (p >> 15) & 7;
                gc = gf * 16 + (l & 15);
                kk = kb * 32 + ((l >> 4) * 8);
                src = Wih1;
            }
            const float* sp = src + ((size_t)e * FH + gc) * HH + kk;
            float4 f0 = *(const float4*)sp;
            float4 f1 = *(const float4*)(sp + 4);
            unsigned short out[8];
            out[0] = f2bf(f0.x); out[1] = f2bf(f0.y); out[2] = f2bf(f0.z); out[3] = f2bf(f0.w);
            out[4] = f2bf(f1.x); out[5] = f2bf(f1.y); out[6] = f2bf(f1.z); out[7] = f2bf(f1.w);
            unsigned short* dst = (arr == 0 ? WR0 : arr == 1 ? WR1 : WG) + (size_t)p * 8;
            *(uint4*)dst = *(uint4*)out;
        } else {
            int p = idx - 3 * NB;
            bsum1[p] = bih1[p] + bhh1[p];
        }
    }
}

// ---------------- embT[e][tok][col(256)][g(4)] bf16 = emb[e,tok] @ Wih0^T + bih0 + bhh0 ----------------
__global__ __launch_bounds__(256)
void embw_kernel(const float* __restrict__ emb, const float* __restrict__ Wih0,
                 const float* __restrict__ bih0, const float* __restrict__ bhh0,
                 unsigned short* __restrict__ embT)
{
    const int e = blockIdx.x, g = blockIdx.y;
    const int tid = threadIdx.x;           // col
    const int gc = g * 256 + tid;
    __shared__ float er[DD * VV];  // [d][tok]
    for (int i = tid; i < VV * DD; i += 256) {
        int tok = i >> 7, d = i & 127;
        er[d * VV + tok] = emb[((size_t)e * VV + tok) * DD + d];
    }
    __syncthreads();
    float acc[VV];
    #pragma unroll
    for (int v = 0; v < VV; v++) acc[v] = 0.f;
    const float* wr = Wih0 + ((size_t)e * FH + gc) * DD;
    for (int d = 0; d < DD; d++) {
        float wv = wr[d];
        #pragma unroll
        for (int v4 = 0; v4 < VV; v4 += 4) {
            float4 ev = *(const float4*)&er[d * VV + v4];
            acc[v4] += ev.x * wv; acc[v4 + 1] += ev.y * wv;
            acc[v4 + 2] += ev.z * wv; acc[v4 + 3] += ev.w * wv;
        }
    }
    float bias = bih0[e * FH + gc] + bhh0[e * FH + gc];
    #pragma unroll 4
    for (int v = 0; v < VV; v++)
        embT[(((size_t)e * VV + v) * 256 + tid) * 4 + g] = f2bf(acc[v] + bias);
}

// ---------------- gating: feat -> MLP -> softmax -> top2 (fp32) ----------------
__global__ __launch_bounds__(128)
void gating_kernel(const int* __restrict__ x, const float* __restrict__ emb,
                   const float* __restrict__ gw1, const float* __restrict__ gb1,
                   const float* __restrict__ g1g, const float* __restrict__ g1b,
                   const float* __restrict__ g1m, const float* __restrict__ g1v,
                   const float* __restrict__ gw2, const float* __restrict__ gb2,
                   const float* __restrict__ g2g, const float* __restrict__ g2b,
                   const float* __restrict__ g2m, const float* __restrict__ g2v,
                   const float* __restrict__ gw3, const float* __restrict__ gb3,
                   int* __restrict__ route_i, float* __restrict__ route_w)
{
    int b = blockIdx.x, tid = threadIdx.x;
    __shared__ int tk[TT];
    __shared__ float feat[DD];
    __shared__ float h1[GG1];
    __shared__ float h2[GG2];
    __shared__ float lg[EE];
    if (tid < TT) tk[tid] = x[b * TT + tid];
    __syncthreads();
    if (tid < DD) {
        float s = 0.f;
        for (int t = 0; t < TT; t++) s += emb[(size_t)tk[t] * DD + tid];
        feat[tid] = s * (1.f / TT);
    }
    __syncthreads();
    for (int j = tid; j < GG1; j += 128) {
        float s = gb1[j];
        const float* wr = gw1 + (size_t)j * DD;
        for (int d = 0; d < DD; d++) s += feat[d] * wr[d];
        float y = (s - g1m[j]) / sqrtf(g1v[j] + 1e-5f) * g1g[j] + g1b[j];
        h1[j] = y > 0.f ? y : 0.f;
    }
    __syncthreads();
    for (int j = tid; j < GG2; j += 128) {
        float s = gb2[j];
        const float* wr = gw2 + (size_t)j * GG1;
        for (int d = 0; d < GG1; d++) s += h1[d] * wr[d];
        float y = (s - g2m[j]) / sqrtf(g2v[j] + 1e-5f) * g2g[j] + g2b[j];
        h2[j] = y > 0.f ? y : 0.f;
    }
    __syncthreads();
    if (tid < EE) {
        float s = gb3[tid];
        const float* wr = gw3 + (size_t)tid * GG2;
        for (int d = 0; d < GG2; d++) s += h2[d] * wr[d];
        lg[tid] = s;
    }
    __syncthreads();
    if (tid == 0) {
        int i0 = 0;
        for (int i = 1; i < EE; i++) if (lg[i] > lg[i0]) i0 = i;
        int i1 = (i0 == 0) ? 1 : 0;
        for (int i = 0; i < EE; i++) if (i != i0 && lg[i] > lg[i1]) i1 = i;
        float e1 = expf(lg[i1] - lg[i0]);
        float inv = 1.f / (1.f + e1);
        route_i[b * 2] = i0; route_i[b * 2 + 1] = i1;
        route_w[b * 2] = inv; route_w[b * 2 + 1] = e1 * inv;
    }
}

// ---------------- route: wave-ballot compaction, 16-padded per-expert regions ----------------
__global__ __launch_bounds__(1024)
void route_kernel(const int* __restrict__ route_i, const float* __restrict__ route_w,
                  int* __restrict__ slot_b, int* __restrict__ slot_k,
                  float* __restrict__ slot_w, int* __restrict__ slot_e)
{
    __shared__ int wcnt[16][EE];
    __shared__ int cnt[EE];
    __shared__ int off[EE + 1];
    int tid = threadIdx.x;
    int lane = tid & 63, wv = tid >> 6;
    int e = route_i[tid];
    unsigned long long below = (1ull << lane) - 1ull;
    int rankw = 0;
    #pragma unroll
    for (int q = 0; q < EE; q++) {
        unsigned long long m = __ballot(e == q);
        if (q == e) rankw = __popcll(m & below);
        if (lane == 0) wcnt[wv][q] = __popcll(m);
    }
    __syncthreads();
    if (tid < EE) {
        int c = 0;
        for (int w2 = 0; w2 < 16; w2++) c += wcnt[w2][tid];
        cnt[tid] = c;
    }
    __syncthreads();
    if (tid == 0) {
        off[0] = 0;
        for (int q = 0; q < EE; q++) off[q + 1] = off[q] + ((cnt[q] + MT - 1) / MT) * MT;
    }
    __syncthreads();
    for (int s = tid; s < SLOTS; s += 1024) {
        int e2 = 0;
        if (s < off[EE]) { for (int q = 0; q < EE; q++) if (s >= off[q]) e2 = q; }
        slot_b[s] = -1; slot_k[s] = 0; slot_w[s] = 0.f; slot_e[s] = e2;
    }
    __syncthreads();
    int rank = rankw;
    for (int w2 = 0; w2 < wv; w2++) rank += wcnt[w2][e];
    int s = off[e] + rank;
    slot_b[s] = tid >> 1; slot_k[s] = tid & 1; slot_w[s] = route_w[tid];
}

// ---------------- persistent LSTM chunk body: ALL weights register-resident ----------------
// 16 slots x 256 cols per block; wave w owns cols [w*32,+32) x 4 gates.
// kb0-3 in VGPRs (128), kb4-7 in AGPRs (128) -- gfx950 MFMA reads A/B from either file.
// All indices compile-time constant (rule #20). Zero weight memory traffic in steady state.
template<int LAYER>
__device__ __forceinline__ void lstm_body(
    int t0, int tcount,
    const unsigned short* __restrict__ WR,
    const unsigned short* __restrict__ embT,
    const unsigned short* __restrict__ zin1,
    const int* __restrict__ x,
    const int* __restrict__ slot_b, const int* __restrict__ slot_e,
    unsigned short* __restrict__ h0seq, float* __restrict__ h1f,
    float* __restrict__ cst, unsigned short* __restrict__ hsv,
    unsigned short (*hbuf)[4096], int* toks)
{
    const int tile = blockIdx.x;
    if (slot_b[tile * MT] < 0) return;
    const int tid = threadIdx.x;
    const int lane = tid & 63;
    const int w = tid >> 6;
    const int e = slot_e[tile * MT];
    const int l15 = lane & 15;
    const int q = lane >> 4;
    const int col0 = w * 32 + l15;
    const int col1 = col0 + 16;
    const int sc0 = (((col0 >> 5) * 64 + 16 * ((col0 >> 3) & 3)) << 3) + (col0 & 7);
    const int sc1 = (((col1 >> 5) * 64 + 16 * ((col1 >> 3) & 3)) << 3) + (col1 & 7);

    const unsigned short* WBg = WR + ((size_t)(e * 8 + w) * 64) * 512 + (size_t)lane * 8;

    // kb0-3 -> VGPRs (pinned "v"), kb4-7 -> AGPRs (pinned "a"); static indices only
    u32x4 wv_[32], wa_[32];
    #pragma unroll
    for (int i = 0; i < 32; i++) wv_[i] = *(const u32x4*)(WBg + (size_t)i * 512);
    #pragma unroll
    for (int i = 0; i < 32; i++) wa_[i] = *(const u32x4*)(WBg + (size_t)(32 + i) * 512);
    #pragma unroll
    for (int i = 0; i < 32; i++) asm volatile("" : "+v"(wv_[i]));
    #pragma unroll
    for (int i = 0; i < 32; i++) asm volatile("" : "+a"(wa_[i]));

    if (LAYER == 0) {
        for (int i = tid; i < tcount * 16; i += 512)
            toks[i] = x[max(slot_b[tile * MT + (i & 15)], 0) * TT + t0 + (i >> 4)];
    }

    if (t0 == 0) {
        *(f32x4*)&hbuf[0][tid * 8] = (f32x4){0.f, 0.f, 0.f, 0.f};
    } else {
        *(bf16x8*)&hbuf[0][tid * 8] = *(const bf16x8*)(hsv + (size_t)tile * 4096 + tid * 8);
    }
    float c[8];
    if (t0 == 0) {
        #pragma unroll
        for (int i = 0; i < 8; i++) c[i] = 0.f;
    } else {
        f32x4 v0 = *(const f32x4*)&cst[((size_t)(tile * 512 + tid)) * 8];
        f32x4 v1 = *(const f32x4*)&cst[((size_t)(tile * 512 + tid)) * 8 + 4];
        c[0]=v0[0]; c[1]=v0[1]; c[2]=v0[2]; c[3]=v0[3];
        c[4]=v1[0]; c[5]=v1[1]; c[6]=v1[2]; c[7]=v1[3];
    }

    __syncthreads();

    int cur = 0;
    for (int t = 0; t < tcount; t++) {
        const int nxt = cur ^ 1;

        // ---- z loads for this step (covered by the MFMA phase below)
        ushort4 za[4], zb[4];
        if (LAYER == 0) {
            #pragma unroll
            for (int reg = 0; reg < 4; reg++) {
                int tok = toks[t * 16 + q * 4 + reg];
                const unsigned short* zp = embT + ((size_t)(e * VV + tok)) * 1024;
                za[reg] = *(const ushort4*)(zp + col0 * 4);
                zb[reg] = *(const ushort4*)(zp + col1 * 4);
            }
        } else {
            const unsigned short* zp = zin1 + ((size_t)(tile * tcount + t)) * 16384;
            #pragma unroll
            for (int g = 0; g < 4; g++) {
                int gfa = g * 16 + w * 2;
                za[g] = *(const ushort4*)(zp + (gfa * 64 + lane) * 4);
                zb[g] = *(const ushort4*)(zp + ((gfa + 1) * 64 + lane) * 4);
            }
        }

        // ---- acc init = z (C-frag layout)
        f32x4 acc[8];
        if (LAYER == 0) {
            #pragma unroll
            for (int reg = 0; reg < 4; reg++) {
                acc[0][reg] = bf2f(za[reg].x); acc[2][reg] = bf2f(za[reg].y);
                acc[4][reg] = bf2f(za[reg].z); acc[6][reg] = bf2f(za[reg].w);
                acc[1][reg] = bf2f(zb[reg].x); acc[3][reg] = bf2f(zb[reg].y);
                acc[5][reg] = bf2f(zb[reg].z); acc[7][reg] = bf2f(zb[reg].w);
            }
        } else {
            #pragma unroll
            for (int g = 0; g < 4; g++) {
                acc[g * 2][0] = bf2f(za[g].x); acc[g * 2][1] = bf2f(za[g].y);
                acc[g * 2][2] = bf2f(za[g].z); acc[g * 2][3] = bf2f(za[g].w);
                acc[g * 2 + 1][0] = bf2f(zb[g].x); acc[g * 2 + 1][1] = bf2f(zb[g].y);
                acc[g * 2 + 1][2] = bf2f(zb[g].z); acc[g * 2 + 1][3] = bf2f(zb[g].w);
            }
        }

        // ---- kb0-3 from VGPRs
        #pragma unroll
        for (int kb = 0; kb < 4; kb++) {
            bf16x8 a = *(const bf16x8*)&hbuf[cur][(kb * 64 + lane) * 8];
            #pragma unroll
            for (int nf = 0; nf < 8; nf++)
                acc[nf] = __builtin_amdgcn_mfma_f32_16x16x32_bf16(
                    a, __builtin_bit_cast(bf16x8, wv_[kb * 8 + nf]), acc[nf], 0, 0, 0);
        }
        // ---- kb4-7 from AGPRs
        #pragma unroll
        for (int kb = 0; kb < 4; kb++) {
            bf16x8 a = *(const bf16x8*)&hbuf[cur][((4 + kb) * 64 + lane) * 8];
            #pragma unroll
            for (int nf = 0; nf < 8; nf++)
                acc[nf] = __builtin_amdgcn_mfma_f32_16x16x32_bf16(
                    a, __builtin_bit_cast(bf16x8, wa_[kb * 8 + nf]), acc[nf], 0, 0, 0);
        }

        // ---- gate phase: lane owns 4 rows x 2 cols
        #pragma unroll
        for (int reg = 0; reg < 4; reg++) {
            int r = q * 4 + reg;
            {   // hc = 0
                float iv = acc[0][reg], fv = acc[2][reg], gv = acc[4][reg], ov = acc[6][reg];
                float cn = sigm(fv) * c[reg * 2] + sigm(iv) * tanh_f(gv);
                float hn = sigm(ov) * tanh_f(cn);
                c[reg * 2] = cn;
                hbuf[nxt][sc0 + r * 8] = f2bf(hn);
                if (LAYER == 1 && t0 + t == TT - 1)
                    h1f[((size_t)(tile * MT + r)) * HH + col0] = hn;
            }
            {   // hc = 1
                float iv = acc[1][reg], fv = acc[3][reg], gv = acc[5][reg], ov = acc[7][reg];
                float cn = sigm(fv) * c[reg * 2 + 1] + sigm(iv) * tanh_f(gv);
                float hn = sigm(ov) * tanh_f(cn);
                c[reg * 2 + 1] = cn;
                hbuf[nxt][sc1 + r * 8] = f2bf(hn);
                if (LAYER == 1 && t0 + t == TT - 1)
                    h1f[((size_t)(tile * MT + r)) * HH + col1] = hn;
            }
        }
        __syncthreads();     // hbuf[nxt] complete — the ONLY barrier per step
        cur = nxt;
        if (LAYER == 0) {
            *(uint4*)(h0seq + ((size_t)(tile * tcount + t)) * 4096 + tid * 8) =
                *(const uint4*)&hbuf[cur][tid * 8];
        }
    }

    // epilogue: save chunk state
    f32x4 v0, v1;
    v0[0]=c[0]; v0[1]=c[1]; v0[2]=c[2]; v0[3]=c[3];
    v1[0]=c[4]; v1[1]=c[5]; v1[2]=c[6]; v1[3]=c[7];
    *(f32x4*)&cst[((size_t)(tile * 512 + tid)) * 8] = v0;
    *(f32x4*)&cst[((size_t)(tile * 512 + tid)) * 8 + 4] = v1;
    *(uint4*)(hsv + (size_t)tile * 4096 + tid * 8) = *(const uint4*)&hbuf[cur][tid * 8];
}

// ---------------- fused skewed dispatch: grid.y==0 -> layer0 chunk t0_0, y==1 -> layer1 chunk t0_1 --
__global__ __launch_bounds__(512, 1)
void lstm_fused(int t0_0, int t0_1, int tcount,
                const unsigned short* __restrict__ WR0, const unsigned short* __restrict__ WR1,
                const unsigned short* __restrict__ embT, const unsigned short* __restrict__ zin1,
                const int* __restrict__ x,
                const int* __restrict__ slot_b, const int* __restrict__ slot_e,
                unsigned short* __restrict__ h0seq, float* __restrict__ h1f,
                float* __restrict__ cst0, float* __restrict__ cst1,
                unsigned short* __restrict__ hsv0, unsigned short* __restrict__ hsv1)
{
    __shared__ unsigned short hbuf[2][4096];        // 16 KB
    __shared__ int toks[CCK * 16];                  // 1 KB
    if (blockIdx.y == 0) {
        if (t0_0 < 0) return;
        lstm_body<0>(t0_0, tcount, WR0, embT, zin1, x, slot_b, slot_e,
                     h0seq, h1f, cst0, hsv0, hbuf, toks);
    } else {
        if (t0_1 < 0) return;
        lstm_body<1>(t0_1, tcount, WR1, embT, zin1, x, slot_b, slot_e,
                     h0seq, h1f, cst1, hsv1, hbuf, toks);
    }
}

// ---------------- zin1[(tile,t)] = h0seq @ Wih1^T + bsum1, C-frag layout ----------------
__global__ __launch_bounds__(256)
void gemm_zin(int tcount,
              const unsigned short* __restrict__ h0seq,
              const unsigned short* __restrict__ WG,
              const float* __restrict__ bsum1,
              const int* __restrict__ slot_b, const int* __restrict__ slot_e,
              unsigned short* __restrict__ zin1)
{
    const int tile = blockIdx.x;
    if (slot_b[tile * MT] < 0) return;
    const int tch = blockIdx.y, nch = blockIdx.z;
    const int tid = threadIdx.x, lane = tid & 63, w = tid >> 6;
    const int e = slot_e[tile * MT];
    __shared__ unsigned short Abuf[32768];
    const unsigned short* Asrc = h0seq + ((size_t)(tile * tcount + tch * 8)) * 4096;
    #pragma unroll
    for (int i = 0; i < 16; i++) {
        int o = (i * 256 + tid) * 8;
        *(bf16x8*)&Abuf[o] = *(const bf16x8*)&Asrc[o];
    }
    __syncthreads();
    const unsigned short* Bp = WG + ((size_t)(e * 64 + nch * 16 + w * 4)) * 4096 + lane * 8;
    f32x4 acc[8][4];
    #pragma unroll
    for (int mf = 0; mf < 8; mf++)
        #pragma unroll
        for (int nfi = 0; nfi < 4; nfi++) acc[mf][nfi] = (f32x4){0.f, 0.f, 0.f, 0.f};
    #pragma unroll
    for (int kb = 0; kb < 8; kb++) {
        bf16x8 b0 = *(const bf16x8*)(Bp + 0 * 4096 + kb * 512);
        bf16x8 b1 = *(const bf16x8*)(Bp + 1 * 4096 + kb * 512);
        bf16x8 b2 = *(const bf16x8*)(Bp + 2 * 4096 + kb * 512);
        bf16x8 b3 = *(const bf16x8*)(Bp + 3 * 4096 + kb * 512);
        #pragma unroll
        for (int mf = 0; mf < 8; mf++) {
            bf16x8 a = *(const bf16x8*)&Abuf[(mf * 8 + kb) * 512 + lane * 8];
            acc[mf][0] = __builtin_amdgcn_mfma_f32_16x16x32_bf16(a, b0, acc[mf][0], 0, 0, 0);
            acc[mf][1] = __builtin_amdgcn_mfma_f32_16x16x32_bf16(a, b1, acc[mf][1], 0, 0, 0);
            acc[mf][2] = __builtin_amdgcn_mfma_f32_16x16x32_bf16(a, b2, acc[mf][2], 0, 0, 0);
            acc[mf][3] = __builtin_amdgcn_mfma_f32_16x16x32_bf16(a, b3, acc[mf][3], 0, 0, 0);
        }
    }
    const int l15 = lane & 15;
    #pragma unroll
    for (int mf = 0; mf < 8; mf++) {
        unsigned short* ob = zin1 + ((size_t)(tile * tcount + tch * 8 + mf)) * 16384;
        #pragma unroll
        for (int nfi = 0; nfi < 4; nfi++) {
            int gf = nch * 16 + w * 4 + nfi;
            float bs = bsum1[e * FH + gf * 16 + l15];
            ushort4 v;
            v.x = f2bf(acc[mf][nfi][0] + bs);
            v.y = f2bf(acc[mf][nfi][1] + bs);
            v.z = f2bf(acc[mf][nfi][2] + bs);
            v.w = f2bf(acc[mf][nfi][3] + bs);
            *(ushort4*)(ob + (size_t)(gf * 64 + lane) * 4) = v;
        }
    }
}

// ---------------- fc per slot, weighted ----------------
__global__ __launch_bounds__(256)
void fc_kernel(const float* __restrict__ fcw, const float* __restrict__ fcb,
               const float* __restrict__ h1f,
               const int* __restrict__ slot_b, const int* __restrict__ slot_k,
               const float* __restrict__ slot_w, const int* __restrict__ slot_e,
               float* __restrict__ wout)
{
    int s = blockIdx.x;
    int b = slot_b[s];
    if (b < 0) return;
    int tid = threadIdx.x;
    __shared__ float hv[HH];
    if (tid < HH) hv[tid] = h1f[(size_t)s * HH + tid];
    __syncthreads();
    int e = slot_e[s], kk = slot_k[s];
    float w = slot_w[s];
    for (int v = tid; v < VV; v += 256) {
        float sacc = fcb[e * VV + v];
        const float* fr = fcw + ((size_t)e * VV + v) * HH;
        #pragma unroll 4
        for (int d = 0; d < HH; d++) sacc += hv[d] * fr[d];
        wout[((size_t)b * 2 + kk) * VV + v] = w * sacc;
    }
}

__global__ void combine_kernel(const float* __restrict__ wout, float* __restrict__ out)
{
    int i = blockIdx.x * blockDim.x + threadIdx.x;
    if (i < BB * VV) {
        int b = i / VV, v = i % VV;
        out[i] = wout[((size_t)b * 2) * VV + v] + wout[((size_t)b * 2 + 1) * VV + v];
    }
}

extern "C" void kernel_launch(void* const* d_in, const int* in_sizes, int n_in,
                              void* d_out, int out_size, void* d_ws, size_t ws_size,
                              hipStream_t stream)
{
    const int*   x    = (const int*)d_in[0];
    const float* emb  = (const float*)d_in[1];
    const float* Wih0 = (const float*)d_in[2];
    const float* Whh0 = (const float*)d_in[3];
    const float* bih0 = (const float*)d_in[4];
    const float* bhh0 = (const float*)d_in[5];
    const float* Wih1 = (const float*)d_in[6];
    const float* Whh1 = (const float*)d_in[7];
    const float* bih1 = (const float*)d_in[8];
    const float* bhh1 = (const float*)d_in[9];
    const float* fcw  = (const float*)d_in[10];
    const float* fcb  = (const float*)d_in[11];
    const float* gw1  = (const float*)d_in[12];
    const float* gb1  = (const float*)d_in[13];
    const float* b1g  = (const float*)d_in[14];
    const float* b1b  = (const float*)d_in[15];
    const float* b1m  = (const float*)d_in[16];
    const float* b1v  = (const float*)d_in[17];
    const float* gw2  = (const float*)d_in[18];
    const float* gb2  = (const float*)d_in[19];
    const float* b2g  = (const float*)d_in[20];
    const float* b2b  = (const float*)d_in[21];
    const float* b2m  = (const float*)d_in[22];
    const float* b2v  = (const float*)d_in[23];
    const float* gw3  = (const float*)d_in[24];
    const float* gb3  = (const float*)d_in[25];

    const size_t NWsh = 262144 * 8;   // ushorts per packed weight array

    char* base = (char*)d_ws;
    size_t o = 0;
    auto alloc = [&](size_t bytes) { char* p = base + o; o = (o + bytes + 255) & ~(size_t)255; return p; };

    unsigned short* WR0  = (unsigned short*)alloc(NWsh * 2);
    unsigned short* WR1  = (unsigned short*)alloc(NWsh * 2);
    unsigned short* WG   = (unsigned short*)alloc(NWsh * 2);
    unsigned short* embT = (unsigned short*)alloc((size_t)EE * VV * FH * 2);
    float* bsum1 = (float*)alloc((size_t)EE * FH * 4);
    float* h1f   = (float*)alloc((size_t)SLOTS * HH * 4);
    float* wout  = (float*)alloc((size_t)BB * 2 * VV * 4);
    float* cst0  = (float*)alloc((size_t)NT * 512 * 8 * 4);
    float* cst1  = (float*)alloc((size_t)NT * 512 * 8 * 4);
    unsigned short* hsv0 = (unsigned short*)alloc((size_t)NT * 4096 * 2);
    unsigned short* hsv1 = (unsigned short*)alloc((size_t)NT * 4096 * 2);
    float* route_w = (float*)alloc((size_t)BB * 2 * 4);
    float* slot_w  = (float*)alloc((size_t)SLOTS * 4);
    int* route_i = (int*)alloc((size_t)BB * 2 * 4);
    int* slot_b  = (int*)alloc((size_t)SLOTS * 4);
    int* slot_k  = (int*)alloc((size_t)SLOTS * 4);
    int* slot_e  = (int*)alloc((size_t)SLOTS * 4);
    unsigned short* h0seq = (unsigned short*)alloc((size_t)NT * CCK * 4096 * 2);   // single-chunk
    unsigned short* zin1  = (unsigned short*)alloc((size_t)NT * CCK * 16384 * 2);  // single-chunk

    prep_kernel<<<3104, 256, 0, stream>>>(Whh0, Wih1, Whh1, bih1, bhh1, WR0, WR1, WG, bsum1);
    embw_kernel<<<dim3(EE, 4), 256, 0, stream>>>(emb, Wih0, bih0, bhh0, embT);
    gating_kernel<<<BB, 128, 0, stream>>>(x, emb, gw1, gb1, b1g, b1b, b1m, b1v,
                                          gw2, gb2, b2g, b2b, b2m, b2v, gw3, gb3,
                                          route_i, route_w);
    route_kernel<<<1, 1024, 0, stream>>>(route_i, route_w, slot_b, slot_k, slot_w, slot_e);

    // chunk-skewed pipeline: dispatch ph runs L0(chunk ph) || L1(chunk ph-1);
    // gemm_zin(chunk ph) between dispatches keeps the L0->G->L1 dependency on the stream.
    const int nch = TT / CCK;   // 5
    for (int ph = 0; ph <= nch; ph++) {
        int t00 = (ph < nch) ? ph * CCK : -1;
        int t01 = (ph > 0) ? (ph - 1) * CCK : -1;
        lstm_fused<<<dim3(NT, 2), 512, 0, stream>>>(t00, t01, CCK, WR0, WR1, embT, zin1, x,
                                                    slot_b, slot_e, h0seq, h1f,
                                                    cst0, cst1, hsv0, hsv1);
        if (ph < nch)
            gemm_zin<<<dim3(NT, CCK / 8, 4), 256, 0, stream>>>(CCK, h0seq, WG, bsum1,
                                                               slot_b, slot_e, zin1);
    }

    fc_kernel<<<SLOTS, 256, 0, stream>>>(fcw, fcb, h1f, slot_b, slot_k, slot_w, slot_e, wout);
    combine_kernel<<<(BB * VV + 255) / 256, 256, 0, stream>>>(wout, (float*)d_out);
}

// Round 15
// 774.367 us; speedup vs baseline: 1.7987x; 1.7987x over previous
//
#include <hip/hip_runtime.h>
#include <hip/hip_bf16.h>
#include <math.h>

#define BB 512
#define TT 80
#define VV 80
#define DD 128
#define HH 256
#define FH 1024
#define EE 8
#define GG1 512
#define GG2 256
#define MT 16
#define NT 72
#define SLOTS (NT*MT)   // 1152
#define CCK 16          // chunk length; 3-deep skewed fusion across chunks

typedef __attribute__((ext_vector_type(8))) short bf16x8;
typedef __attribute__((ext_vector_type(4))) float f32x4;
typedef __attribute__((ext_vector_type(4))) unsigned int u32x4;

__device__ __forceinline__ float bf2f(unsigned short u) {
    unsigned int v = ((unsigned int)u) << 16;
    return __builtin_bit_cast(float, v);
}
__device__ __forceinline__ unsigned short f2bf(float f) {
    __hip_bfloat16 h = __float2bfloat16(f);
    return __builtin_bit_cast(unsigned short, h);
}
__device__ __forceinline__ float sigm(float x) { return 1.f / (1.f + __expf(-x)); }
__device__ __forceinline__ float tanh_f(float x) {
    float ax = fabsf(x);
    float r = 1.f - 2.f / (__expf(2.f * ax) + 1.f);
    return x < 0.f ? -r : r;
}

// ---------------- prep: pack recurrent weights (full-width wave layout) + Wih1 + bias sums --------
__global__ void prep_kernel(const float* __restrict__ Whh0, const float* __restrict__ Wih1,
                            const float* __restrict__ Whh1,
                            const float* __restrict__ bih1, const float* __restrict__ bhh1,
                            unsigned short* __restrict__ WR0, unsigned short* __restrict__ WR1,
                            unsigned short* __restrict__ WG, float* __restrict__ bsum1)
{
    const int NB = 262144;
    const int ntot = 3 * NB + EE * FH;
    for (int idx = blockIdx.x * blockDim.x + threadIdx.x; idx < ntot;
         idx += gridDim.x * blockDim.x) {
        if (idx < 3 * NB) {
            int arr = idx / NB;
            int p = idx - arr * NB;
            int gc, kk, e;
            const float* src;
            if (arr < 2) {
                int l = p & 63, nf = (p >> 6) & 7, kb = (p >> 9) & 7, w = (p >> 12) & 7;
                e = (p >> 15) & 7;
                int g = nf >> 1, hc = nf & 1;
                gc = g * 256 + w * 32 + hc * 16 + (l & 15);
                kk = kb * 32 + ((l >> 4) * 8);
                src = (arr == 0) ? Whh0 : Whh1;
            } else {
                int l = p & 63, kb = (p >> 6) & 7, gf = (p >> 9) & 63; e = (p >> 15) & 7;
                gc = gf * 16 + (l & 15);
                kk = kb * 32 + ((l >> 4) * 8);
                src = Wih1;
            }
            const float* sp = src + ((size_t)e * FH + gc) * HH + kk;
            float4 f0 = *(const float4*)sp;
            float4 f1 = *(const float4*)(sp + 4);
            unsigned short out[8];
            out[0] = f2bf(f0.x); out[1] = f2bf(f0.y); out[2] = f2bf(f0.z); out[3] = f2bf(f0.w);
            out[4] = f2bf(f1.x); out[5] = f2bf(f1.y); out[6] = f2bf(f1.z); out[7] = f2bf(f1.w);
            unsigned short* dst = (arr == 0 ? WR0 : arr == 1 ? WR1 : WG) + (size_t)p * 8;
            *(uint4*)dst = *(uint4*)out;
        } else {
            int p = idx - 3 * NB;
            bsum1[p] = bih1[p] + bhh1[p];
        }
    }
}

// ---------------- embT[e][tok][col(256)][g(4)] bf16 = emb[e,tok] @ Wih0^T + bih0 + bhh0 ----------------
__global__ __launch_bounds__(256)
void embw_kernel(const float* __restrict__ emb, const float* __restrict__ Wih0,
                 const float* __restrict__ bih0, const float* __restrict__ bhh0,
                 unsigned short* __restrict__ embT)
{
    const int e = blockIdx.x, g = blockIdx.y;
    const int tid = threadIdx.x;
    const int gc = g * 256 + tid;
    __shared__ float er[DD * VV];
    for (int i = tid; i < VV * DD; i += 256) {
        int tok = i >> 7, d = i & 127;
        er[d * VV + tok] = emb[((size_t)e * VV + tok) * DD + d];
    }
    __syncthreads();
    float acc[VV];
    #pragma unroll
    for (int v = 0; v < VV; v++) acc[v] = 0.f;
    const float* wr = Wih0 + ((size_t)e * FH + gc) * DD;
    for (int d = 0; d < DD; d++) {
        float wv = wr[d];
        #pragma unroll
        for (int v4 = 0; v4 < VV; v4 += 4) {
            float4 ev = *(const float4*)&er[d * VV + v4];
            acc[v4] += ev.x * wv; acc[v4 + 1] += ev.y * wv;
            acc[v4 + 2] += ev.z * wv; acc[v4 + 3] += ev.w * wv;
        }
    }
    float bias = bih0[e * FH + gc] + bhh0[e * FH + gc];
    #pragma unroll 4
    for (int v = 0; v < VV; v++)
        embT[(((size_t)e * VV + v) * 256 + tid) * 4 + g] = f2bf(acc[v] + bias);
}

// ---------------- gating: feat -> MLP -> softmax -> top2 (fp32) ----------------
__global__ __launch_bounds__(128)
void gating_kernel(const int* __restrict__ x, const float* __restrict__ emb,
                   const float* __restrict__ gw1, const float* __restrict__ gb1,
                   const float* __restrict__ g1g, const float* __restrict__ g1b,
                   const float* __restrict__ g1m, const float* __restrict__ g1v,
                   const float* __restrict__ gw2, const float* __restrict__ gb2,
                   const float* __restrict__ g2g, const float* __restrict__ g2b,
                   const float* __restrict__ g2m, const float* __restrict__ g2v,
                   const float* __restrict__ gw3, const float* __restrict__ gb3,
                   int* __restrict__ route_i, float* __restrict__ route_w)
{
    int b = blockIdx.x, tid = threadIdx.x;
    __shared__ int tk[TT];
    __shared__ float feat[DD];
    __shared__ float h1[GG1];
    __shared__ float h2[GG2];
    __shared__ float lg[EE];
    if (tid < TT) tk[tid] = x[b * TT + tid];
    __syncthreads();
    if (tid < DD) {
        float s = 0.f;
        for (int t = 0; t < TT; t++) s += emb[(size_t)tk[t] * DD + tid];
        feat[tid] = s * (1.f / TT);
    }
    __syncthreads();
    for (int j = tid; j < GG1; j += 128) {
        float s = gb1[j];
        const float* wr = gw1 + (size_t)j * DD;
        for (int d = 0; d < DD; d++) s += feat[d] * wr[d];
        float y = (s - g1m[j]) / sqrtf(g1v[j] + 1e-5f) * g1g[j] + g1b[j];
        h1[j] = y > 0.f ? y : 0.f;
    }
    __syncthreads();
    for (int j = tid; j < GG2; j += 128) {
        float s = gb2[j];
        const float* wr = gw2 + (size_t)j * GG1;
        for (int d = 0; d < GG1; d++) s += h1[d] * wr[d];
        float y = (s - g2m[j]) / sqrtf(g2v[j] + 1e-5f) * g2g[j] + g2b[j];
        h2[j] = y > 0.f ? y : 0.f;
    }
    __syncthreads();
    if (tid < EE) {
        float s = gb3[tid];
        const float* wr = gw3 + (size_t)tid * GG2;
        for (int d = 0; d < GG2; d++) s += h2[d] * wr[d];
        lg[tid] = s;
    }
    __syncthreads();
    if (tid == 0) {
        int i0 = 0;
        for (int i = 1; i < EE; i++) if (lg[i] > lg[i0]) i0 = i;
        int i1 = (i0 == 0) ? 1 : 0;
        for (int i = 0; i < EE; i++) if (i != i0 && lg[i] > lg[i1]) i1 = i;
        float e1 = expf(lg[i1] - lg[i0]);
        float inv = 1.f / (1.f + e1);
        route_i[b * 2] = i0; route_i[b * 2 + 1] = i1;
        route_w[b * 2] = inv; route_w[b * 2 + 1] = e1 * inv;
    }
}

// ---------------- route: wave-ballot compaction, 16-padded per-expert regions ----------------
__global__ __launch_bounds__(1024)
void route_kernel(const int* __restrict__ route_i, const float* __restrict__ route_w,
                  int* __restrict__ slot_b, int* __restrict__ slot_k,
                  float* __restrict__ slot_w, int* __restrict__ slot_e)
{
    __shared__ int wcnt[16][EE];
    __shared__ int cnt[EE];
    __shared__ int off[EE + 1];
    int tid = threadIdx.x;
    int lane = tid & 63, wv = tid >> 6;
    int e = route_i[tid];
    unsigned long long below = (1ull << lane) - 1ull;
    int rankw = 0;
    #pragma unroll
    for (int q = 0; q < EE; q++) {
        unsigned long long m = __ballot(e == q);
        if (q == e) rankw = __popcll(m & below);
        if (lane == 0) wcnt[wv][q] = __popcll(m);
    }
    __syncthreads();
    if (tid < EE) {
        int c = 0;
        for (int w2 = 0; w2 < 16; w2++) c += wcnt[w2][tid];
        cnt[tid] = c;
    }
    __syncthreads();
    if (tid == 0) {
        off[0] = 0;
        for (int q = 0; q < EE; q++) off[q + 1] = off[q] + ((cnt[q] + MT - 1) / MT) * MT;
    }
    __syncthreads();
    for (int s = tid; s < SLOTS; s += 1024) {
        int e2 = 0;
        if (s < off[EE]) { for (int q = 0; q < EE; q++) if (s >= off[q]) e2 = q; }
        slot_b[s] = -1; slot_k[s] = 0; slot_w[s] = 0.f; slot_e[s] = e2;
    }
    __syncthreads();
    int rank = rankw;
    for (int w2 = 0; w2 < wv; w2++) rank += wcnt[w2][e];
    int s = off[e] + rank;
    slot_b[s] = tid >> 1; slot_k[s] = tid & 1; slot_w[s] = route_w[tid];
}

// ---------------- persistent LSTM chunk body (r13 step flow + z double-buffer prefetch) ---------
template<int LAYER>
__device__ __forceinline__ void lstm_body(
    int t0, int tcount,
    const unsigned short* __restrict__ WR,
    const unsigned short* __restrict__ embT,
    const unsigned short* __restrict__ zin,
    const int* __restrict__ x,
    const int* __restrict__ slot_b, const int* __restrict__ slot_e,
    unsigned short* __restrict__ h0seq, float* __restrict__ h1f,
    float* __restrict__ cst, unsigned short* __restrict__ hsv,
    unsigned short (*wlds)[8][8][512], unsigned short (*hbuf)[4096], int* toks)
{
    const int tile = blockIdx.x;
    if (slot_b[tile * MT] < 0) return;
    const int tid = threadIdx.x;
    const int lane = tid & 63;
    const int w = tid >> 6;
    const int e = slot_e[tile * MT];
    const int l15 = lane & 15;
    const int q = lane >> 4;
    const int col0 = w * 32 + l15;
    const int col1 = col0 + 16;
    const int sc0 = (((col0 >> 5) * 64 + 16 * ((col0 >> 3) & 3)) << 3) + (col0 & 7);
    const int sc1 = (((col1 >> 5) * 64 + 16 * ((col1 >> 3) & 3)) << 3) + (col1 & 7);

    const unsigned short* WBg = WR + ((size_t)(e * 8 + w) * 64) * 512 + (size_t)lane * 8;

    // kb0-3 register-resident: 32 frags = 128 regs, static indices only (rule #20)
    u32x4 wres[32];
    #pragma unroll
    for (int i = 0; i < 32; i++) wres[i] = *(const u32x4*)(WBg + (size_t)i * 512);
    #pragma unroll
    for (int i = 0; i < 32; i++) asm volatile("" : "+v"(wres[i]));

    // kb4-5 -> LDS (each wave copies its own 32 KB slab)
    #pragma unroll
    for (int i = 0; i < 16; i++)
        *(uint4*)&wlds[i >> 3][w][i & 7][lane * 8] = *(const uint4*)(WBg + (size_t)(32 + i) * 512);

    if (LAYER == 0) {
        for (int i = tid; i < tcount * 16; i += 512)
            toks[i] = x[max(slot_b[tile * MT + (i & 15)], 0) * TT + t0 + (i >> 4)];
    }

    if (t0 == 0) {
        *(f32x4*)&hbuf[0][tid * 8] = (f32x4){0.f, 0.f, 0.f, 0.f};
    } else {
        *(bf16x8*)&hbuf[0][tid * 8] = *(const bf16x8*)(hsv + (size_t)tile * 4096 + tid * 8);
    }
    float c[8];
    if (t0 == 0) {
        #pragma unroll
        for (int i = 0; i < 8; i++) c[i] = 0.f;
    } else {
        f32x4 v0 = *(const f32x4*)&cst[((size_t)(tile * 512 + tid)) * 8];
        f32x4 v1 = *(const f32x4*)&cst[((size_t)(tile * 512 + tid)) * 8 + 4];
        c[0]=v0[0]; c[1]=v0[1]; c[2]=v0[2]; c[3]=v0[3];
        c[4]=v1[0]; c[5]=v1[1]; c[6]=v1[2]; c[7]=v1[3];
    }

    __syncthreads();

    // ---- z prefetch for t = 0 (r4/r5 proven pattern)
    ushort4 za[4], zb[4];
    if (LAYER == 0) {
        #pragma unroll
        for (int reg = 0; reg < 4; reg++) {
            int tok = toks[q * 4 + reg];
            const unsigned short* zp = embT + ((size_t)(e * VV + tok)) * 1024;
            za[reg] = *(const ushort4*)(zp + col0 * 4);
            zb[reg] = *(const ushort4*)(zp + col1 * 4);
        }
    } else {
        const unsigned short* zp = zin + ((size_t)(tile * tcount)) * 16384;
        #pragma unroll
        for (int g = 0; g < 4; g++) {
            int gfa = g * 16 + w * 2;
            za[g] = *(const ushort4*)(zp + (gfa * 64 + lane) * 4);
            zb[g] = *(const ushort4*)(zp + ((gfa + 1) * 64 + lane) * 4);
        }
    }

    int cur = 0;
    for (int t = 0; t < tcount; t++) {
        const int nxt = cur ^ 1;

        // ---- prefetch NEXT step's z (full step of latency cover)
        ushort4 zan[4], zbn[4];
        {
            int tn = (t + 1 < tcount) ? t + 1 : t;
            if (LAYER == 0) {
                #pragma unroll
                for (int reg = 0; reg < 4; reg++) {
                    int tok = toks[tn * 16 + q * 4 + reg];
                    const unsigned short* zp = embT + ((size_t)(e * VV + tok)) * 1024;
                    zan[reg] = *(const ushort4*)(zp + col0 * 4);
                    zbn[reg] = *(const ushort4*)(zp + col1 * 4);
                }
            } else {
                const unsigned short* zp = zin + ((size_t)(tile * tcount + tn)) * 16384;
                #pragma unroll
                for (int g = 0; g < 4; g++) {
                    int gfa = g * 16 + w * 2;
                    zan[g] = *(const ushort4*)(zp + (gfa * 64 + lane) * 4);
                    zbn[g] = *(const ushort4*)(zp + ((gfa + 1) * 64 + lane) * 4);
                }
            }
        }

        // ---- stream kb6 (plain loads; compiler schedules + inserts waits)
        u32x4 ws[8];
        #pragma unroll
        for (int nf = 0; nf < 8; nf++) ws[nf] = *(const u32x4*)(WBg + (size_t)(48 + nf) * 512);

        // ---- acc init = z (C-frag layout), z prefetched a full step earlier
        f32x4 acc[8];
        if (LAYER == 0) {
            #pragma unroll
            for (int reg = 0; reg < 4; reg++) {
                acc[0][reg] = bf2f(za[reg].x); acc[2][reg] = bf2f(za[reg].y);
                acc[4][reg] = bf2f(za[reg].z); acc[6][reg] = bf2f(za[reg].w);
                acc[1][reg] = bf2f(zb[reg].x); acc[3][reg] = bf2f(zb[reg].y);
                acc[5][reg] = bf2f(zb[reg].z); acc[7][reg] = bf2f(zb[reg].w);
            }
        } else {
            #pragma unroll
            for (int g = 0; g < 4; g++) {
                acc[g * 2][0] = bf2f(za[g].x); acc[g * 2][1] = bf2f(za[g].y);
                acc[g * 2][2] = bf2f(za[g].z); acc[g * 2][3] = bf2f(za[g].w);
                acc[g * 2 + 1][0] = bf2f(zb[g].x); acc[g * 2 + 1][1] = bf2f(zb[g].y);
                acc[g * 2 + 1][2] = bf2f(zb[g].z); acc[g * 2 + 1][3] = bf2f(zb[g].w);
            }
        }

        // ---- kb0-3: register-resident
        #pragma unroll
        for (int kb = 0; kb < 4; kb++) {
            bf16x8 a = *(const bf16x8*)&hbuf[cur][(kb * 64 + lane) * 8];
            #pragma unroll
            for (int nf = 0; nf < 8; nf++)
                acc[nf] = __builtin_amdgcn_mfma_f32_16x16x32_bf16(
                    a, __builtin_bit_cast(bf16x8, wres[kb * 8 + nf]), acc[nf], 0, 0, 0);
        }

        // ---- kb4-5: LDS-resident
        #pragma unroll
        for (int kbi = 0; kbi < 2; kbi++) {
            bf16x8 a = *(const bf16x8*)&hbuf[cur][((4 + kbi) * 64 + lane) * 8];
            #pragma unroll
            for (int nf = 0; nf < 8; nf++) {
                bf16x8 wl = *(const bf16x8*)&wlds[kbi][w][nf][lane * 8];
                acc[nf] = __builtin_amdgcn_mfma_f32_16x16x32_bf16(a, wl, acc[nf], 0, 0, 0);
            }
        }

        // ---- kb6: streamed (ws); then reload ws = kb7
        {
            bf16x8 a = *(const bf16x8*)&hbuf[cur][(6 * 64 + lane) * 8];
            #pragma unroll
            for (int nf = 0; nf < 8; nf++)
                acc[nf] = __builtin_amdgcn_mfma_f32_16x16x32_bf16(
                    a, __builtin_bit_cast(bf16x8, ws[nf]), acc[nf], 0, 0, 0);
        }
        #pragma unroll
        for (int nf = 0; nf < 8; nf++) ws[nf] = *(const u32x4*)(WBg + (size_t)(56 + nf) * 512);
        {
            bf16x8 a = *(const bf16x8*)&hbuf[cur][(7 * 64 + lane) * 8];
            #pragma unroll
            for (int nf = 0; nf < 8; nf++)
                acc[nf] = __builtin_amdgcn_mfma_f32_16x16x32_bf16(
                    a, __builtin_bit_cast(bf16x8, ws[nf]), acc[nf], 0, 0, 0);
        }

        // ---- gate phase: lane owns 4 rows x 2 cols
        #pragma unroll
        for (int reg = 0; reg < 4; reg++) {
            int r = q * 4 + reg;
            {   // hc = 0
                float iv = acc[0][reg], fv = acc[2][reg], gv = acc[4][reg], ov = acc[6][reg];
                float cn = sigm(fv) * c[reg * 2] + sigm(iv) * tanh_f(gv);
                float hn = sigm(ov) * tanh_f(cn);
                c[reg * 2] = cn;
                hbuf[nxt][sc0 + r * 8] = f2bf(hn);
                if (LAYER == 1 && t0 + t == TT - 1)
                    h1f[((size_t)(tile * MT + r)) * HH + col0] = hn;
            }
            {   // hc = 1
                float iv = acc[1][reg], fv = acc[3][reg], gv = acc[5][reg], ov = acc[7][reg];
                float cn = sigm(fv) * c[reg * 2 + 1] + sigm(iv) * tanh_f(gv);
                float hn = sigm(ov) * tanh_f(cn);
                c[reg * 2 + 1] = cn;
                hbuf[nxt][sc1 + r * 8] = f2bf(hn);
                if (LAYER == 1 && t0 + t == TT - 1)
                    h1f[((size_t)(tile * MT + r)) * HH + col1] = hn;
            }
        }
        __syncthreads();     // hbuf[nxt] complete — the ONLY barrier per step
        cur = nxt;
        #pragma unroll
        for (int i = 0; i < 4; i++) { za[i] = zan[i]; zb[i] = zbn[i]; }
        if (LAYER == 0) {
            *(uint4*)(h0seq + ((size_t)(tile * tcount + t)) * 4096 + tid * 8) =
                *(const uint4*)&hbuf[cur][tid * 8];
        }
    }

    // epilogue: save chunk state
    f32x4 v0, v1;
    v0[0]=c[0]; v0[1]=c[1]; v0[2]=c[2]; v0[3]=c[3];
    v1[0]=c[4]; v1[1]=c[5]; v1[2]=c[6]; v1[3]=c[7];
    *(f32x4*)&cst[((size_t)(tile * 512 + tid)) * 8] = v0;
    *(f32x4*)&cst[((size_t)(tile * 512 + tid)) * 8 + 4] = v1;
    *(uint4*)(hsv + (size_t)tile * 4096 + tid * 8) = *(const uint4*)&hbuf[cur][tid * 8];
}

// ---------------- gemm body (512-thread): zin_w[(tile,t)] = h0_r @ Wih1^T + bsum1 ----------------
__device__ __forceinline__ void gemm_body(
    int tcount,
    const unsigned short* __restrict__ h0seq,
    const unsigned short* __restrict__ WG,
    const float* __restrict__ bsum1,
    const int* __restrict__ slot_b, const int* __restrict__ slot_e,
    unsigned short* __restrict__ zin1,
    unsigned short* Abuf)
{
    const int tile = blockIdx.x;
    if (slot_b[tile * MT] < 0) return;
    const int tid = threadIdx.x, lane = tid & 63, w = tid >> 6;
    const int e = slot_e[tile * MT];
    const int l15 = lane & 15;
    for (int tch = 0; tch < tcount / 8; tch++) {
        const unsigned short* Asrc = h0seq + ((size_t)(tile * tcount + tch * 8)) * 4096;
        #pragma unroll
        for (int i = 0; i < 8; i++) {
            int o = (i * 512 + tid) * 8;
            *(bf16x8*)&Abuf[o] = *(const bf16x8*)&Asrc[o];
        }
        __syncthreads();
        #pragma unroll
        for (int gh = 0; gh < 2; gh++) {
            const unsigned short* Bp = WG + ((size_t)(e * 64 + w * 8 + gh * 4)) * 4096 + (size_t)lane * 8;
            f32x4 acc[8][4];
            #pragma unroll
            for (int mf = 0; mf < 8; mf++)
                #pragma unroll
                for (int nfi = 0; nfi < 4; nfi++) acc[mf][nfi] = (f32x4){0.f, 0.f, 0.f, 0.f};
            #pragma unroll
            for (int kb = 0; kb < 8; kb++) {
                bf16x8 b0 = *(const bf16x8*)(Bp + 0 * 4096 + kb * 512);
                bf16x8 b1 = *(const bf16x8*)(Bp + 1 * 4096 + kb * 512);
                bf16x8 b2 = *(const bf16x8*)(Bp + 2 * 4096 + kb * 512);
                bf16x8 b3 = *(const bf16x8*)(Bp + 3 * 4096 + kb * 512);
                #pragma unroll
                for (int mf = 0; mf < 8; mf++) {
                    bf16x8 a = *(const bf16x8*)&Abuf[(mf * 8 + kb) * 512 + lane * 8];
                    acc[mf][0] = __builtin_amdgcn_mfma_f32_16x16x32_bf16(a, b0, acc[mf][0], 0, 0, 0);
                    acc[mf][1] = __builtin_amdgcn_mfma_f32_16x16x32_bf16(a, b1, acc[mf][1], 0, 0, 0);
                    acc[mf][2] = __builtin_amdgcn_mfma_f32_16x16x32_bf16(a, b2, acc[mf][2], 0, 0, 0);
                    acc[mf][3] = __builtin_amdgcn_mfma_f32_16x16x32_bf16(a, b3, acc[mf][3], 0, 0, 0);
                }
            }
            #pragma unroll
            for (int mf = 0; mf < 8; mf++) {
                unsigned short* ob = zin1 + ((size_t)(tile * tcount + tch * 8 + mf)) * 16384;
                #pragma unroll
                for (int nfi = 0; nfi < 4; nfi++) {
                    int gf = w * 8 + gh * 4 + nfi;
                    float bs = bsum1[e * FH + gf * 16 + l15];
                    ushort4 v;
                    v.x = f2bf(acc[mf][nfi][0] + bs);
                    v.y = f2bf(acc[mf][nfi][1] + bs);
                    v.z = f2bf(acc[mf][nfi][2] + bs);
                    v.w = f2bf(acc[mf][nfi][3] + bs);
                    *(ushort4*)(ob + (size_t)(gf * 64 + lane) * 4) = v;
                }
            }
        }
        __syncthreads();
    }
}

// -------- fused 3-deep skewed dispatch: y=0 -> L0(t00), y=1 -> L1(t01), y=2 -> G(tg) --------
__global__ __launch_bounds__(512, 1)
void lstm_fused(int t00, int t01, int tg, int tcount,
                const unsigned short* __restrict__ WR0, const unsigned short* __restrict__ WR1,
                const unsigned short* __restrict__ WG, const float* __restrict__ bsum1,
                const unsigned short* __restrict__ embT,
                unsigned short* __restrict__ h0_w, const unsigned short* __restrict__ h0_r,
                unsigned short* __restrict__ zin_w, const unsigned short* __restrict__ zin_r,
                const int* __restrict__ x,
                const int* __restrict__ slot_b, const int* __restrict__ slot_e,
                float* __restrict__ h1f,
                float* __restrict__ cst0, float* __restrict__ cst1,
                unsigned short* __restrict__ hsv0, unsigned short* __restrict__ hsv1)
{
    __shared__ unsigned short wlds[2][8][8][512];   // 128 KB (lstm); first 64 KB doubles as gemm Abuf
    __shared__ unsigned short hbuf[2][4096];        // 16 KB
    __shared__ int toks[CCK * 16];                  // 1 KB
    if (blockIdx.y == 0) {
        if (t00 < 0) return;
        lstm_body<0>(t00, tcount, WR0, embT, nullptr, x, slot_b, slot_e,
                     h0_w, h1f, cst0, hsv0, wlds, hbuf, toks);
    } else if (blockIdx.y == 1) {
        if (t01 < 0) return;
        lstm_body<1>(t01, tcount, WR1, embT, zin_r, x, slot_b, slot_e,
                     nullptr, h1f, cst1, hsv1, wlds, hbuf, toks);
    } else {
        if (tg < 0) return;
        gemm_body(tcount, h0_r, WG, bsum1, slot_b, slot_e, zin_w, &wlds[0][0][0][0]);
    }
}

// ---------------- fc per slot, weighted ----------------
__global__ __launch_bounds__(256)
void fc_kernel(const float* __restrict__ fcw, const float* __restrict__ fcb,
               const float* __restrict__ h1f,
               const int* __restrict__ slot_b, const int* __restrict__ slot_k,
               const float* __restrict__ slot_w, const int* __restrict__ slot_e,
               float* __restrict__ wout)
{
    int s = blockIdx.x;
    int b = slot_b[s];
    if (b < 0) return;
    int tid = threadIdx.x;
    __shared__ float hv[HH];
    if (tid < HH) hv[tid] = h1f[(size_t)s * HH + tid];
    __syncthreads();
    int e = slot_e[s], kk = slot_k[s];
    float w = slot_w[s];
    for (int v = tid; v < VV; v += 256) {
        float sacc = fcb[e * VV + v];
        const float* fr = fcw + ((size_t)e * VV + v) * HH;
        #pragma unroll 4
        for (int d = 0; d < HH; d++) sacc += hv[d] * fr[d];
        wout[((size_t)b * 2 + kk) * VV + v] = w * sacc;
    }
}

__global__ void combine_kernel(const float* __restrict__ wout, float* __restrict__ out)
{
    int i = blockIdx.x * blockDim.x + threadIdx.x;
    if (i < BB * VV) {
        int b = i / VV, v = i % VV;
        out[i] = wout[((size_t)b * 2) * VV + v] + wout[((size_t)b * 2 + 1) * VV + v];
    }
}

extern "C" void kernel_launch(void* const* d_in, const int* in_sizes, int n_in,
                              void* d_out, int out_size, void* d_ws, size_t ws_size,
                              hipStream_t stream)
{
    const int*   x    = (const int*)d_in[0];
    const float* emb  = (const float*)d_in[1];
    const float* Wih0 = (const float*)d_in[2];
    const float* Whh0 = (const float*)d_in[3];
    const float* bih0 = (const float*)d_in[4];
    const float* bhh0 = (const float*)d_in[5];
    const float* Wih1 = (const float*)d_in[6];
    const float* Whh1 = (const float*)d_in[7];
    const float* bih1 = (const float*)d_in[8];
    const float* bhh1 = (const float*)d_in[9];
    const float* fcw  = (const float*)d_in[10];
    const float* fcb  = (const float*)d_in[11];
    const float* gw1  = (const float*)d_in[12];
    const float* gb1  = (const float*)d_in[13];
    const float* b1g  = (const float*)d_in[14];
    const float* b1b  = (const float*)d_in[15];
    const float* b1m  = (const float*)d_in[16];
    const float* b1v  = (const float*)d_in[17];
    const float* gw2  = (const float*)d_in[18];
    const float* gb2  = (const float*)d_in[19];
    const float* b2g  = (const float*)d_in[20];
    const float* b2b  = (const float*)d_in[21];
    const float* b2m  = (const float*)d_in[22];
    const float* b2v  = (const float*)d_in[23];
    const float* gw3  = (const float*)d_in[24];
    const float* gb3  = (const float*)d_in[25];

    const size_t NWsh = 262144 * 8;   // ushorts per packed weight array

    char* base = (char*)d_ws;
    size_t o = 0;
    auto alloc = [&](size_t bytes) { char* p = base + o; o = (o + bytes + 255) & ~(size_t)255; return p; };

    unsigned short* WR0  = (unsigned short*)alloc(NWsh * 2);
    unsigned short* WR1  = (unsigned short*)alloc(NWsh * 2);
    unsigned short* WG   = (unsigned short*)alloc(NWsh * 2);
    unsigned short* embT = (unsigned short*)alloc((size_t)EE * VV * FH * 2);
    float* bsum1 = (float*)alloc((size_t)EE * FH * 4);
    float* h1f   = (float*)alloc((size_t)SLOTS * HH * 4);
    float* wout  = (float*)alloc((size_t)BB * 2 * VV * 4);
    float* cst0  = (float*)alloc((size_t)NT * 512 * 8 * 4);
    float* cst1  = (float*)alloc((size_t)NT * 512 * 8 * 4);
    unsigned short* hsv0 = (unsigned short*)alloc((size_t)NT * 4096 * 2);
    unsigned short* hsv1 = (unsigned short*)alloc((size_t)NT * 4096 * 2);
    float* route_w = (float*)alloc((size_t)BB * 2 * 4);
    float* slot_w  = (float*)alloc((size_t)SLOTS * 4);
    int* route_i = (int*)alloc((size_t)BB * 2 * 4);
    int* slot_b  = (int*)alloc((size_t)SLOTS * 4);
    int* slot_k  = (int*)alloc((size_t)SLOTS * 4);
    int* slot_e  = (int*)alloc((size_t)SLOTS * 4);
    unsigned short* h0seqA = (unsigned short*)alloc((size_t)NT * CCK * 4096 * 2);
    unsigned short* h0seqB = (unsigned short*)alloc((size_t)NT * CCK * 4096 * 2);
    unsigned short* zinA   = (unsigned short*)alloc((size_t)NT * CCK * 16384 * 2);
    unsigned short* zinB   = (unsigned short*)alloc((size_t)NT * CCK * 16384 * 2);

    prep_kernel<<<3104, 256, 0, stream>>>(Whh0, Wih1, Whh1, bih1, bhh1, WR0, WR1, WG, bsum1);
    embw_kernel<<<dim3(EE, 4), 256, 0, stream>>>(emb, Wih0, bih0, bhh0, embT);
    gating_kernel<<<BB, 128, 0, stream>>>(x, emb, gw1, gb1, b1g, b1b, b1m, b1v,
                                          gw2, gb2, b2g, b2b, b2m, b2v, gw3, gb3,
                                          route_i, route_w);
    route_kernel<<<1, 1024, 0, stream>>>(route_i, route_w, slot_b, slot_k, slot_w, slot_e);

    // 3-deep skewed pipeline: dispatch ph = { L0(ph) || G(ph-1) || L1(ph-2) }.
    // Buffers by parity: L0(ph) writes h0seq[ph&1]; G(ph-1) reads h0seq[(ph-1)&1],
    // writes zin[(ph-1)&1]; L1(ph-2) reads zin[(ph-2)&1]. Stream order carries deps.
    const int nch = TT / CCK;   // 5
    for (int ph = 0; ph <= nch + 1; ph++) {
        int t00 = (ph < nch) ? ph * CCK : -1;
        int tg  = (ph - 1 >= 0 && ph - 1 < nch) ? (ph - 1) * CCK : -1;
        int t01 = (ph - 2 >= 0 && ph - 2 < nch) ? (ph - 2) * CCK : -1;
        unsigned short* h0_w = (ph & 1) ? h0seqB : h0seqA;
        unsigned short* h0_r = ((ph - 1) & 1) ? h0seqB : h0seqA;
        unsigned short* zn_w = ((ph - 1) & 1) ? zinB : zinA;
        unsigned short* zn_r = ((ph - 2) & 1) ? zinB : zinA;
        lstm_fused<<<dim3(NT, 3), 512, 0, stream>>>(t00, t01, tg, CCK, WR0, WR1, WG, bsum1,
                                                    embT, h0_w, h0_r, zn_w, zn_r, x,
                                                    slot_b, slot_e, h1f,
                                                    cst0, cst1, hsv0, hsv1);
    }

    fc_kernel<<<SLOTS, 256, 0, stream>>>(fcw, fcb, h1f, slot_b, slot_k, slot_w, slot_e, wout);
    combine_kernel<<<(BB * VV + 255) / 256, 256, 0, stream>>>(wout, (float*)d_out);
}